// Round 1
// baseline (410.562 us; speedup 1.0000x reference)
//
#include <hip/hip_runtime.h>
#include <hip/hip_bf16.h>
#include <math.h>

#define DMODEL 256
#define NHEADS 8
#define DK 32
#define NKEYS 64
#define FFN 1024
#define NROWS 4096   // B*Q
#define QTOT 2048

using bf16x8 = __attribute__((ext_vector_type(8))) short;
using f32x4  = __attribute__((ext_vector_type(4))) float;

static __device__ __forceinline__ short f2bf(float f) {
    union { float f; unsigned u; } v; v.f = f;
    unsigned r = v.u + 0x7fffu + ((v.u >> 16) & 1u);
    return (short)(r >> 16);
}

// ---------------- K0: weight convert + transpose to bf16 -------------------
__global__ void wconv(const float* __restrict__ Wk, const float* __restrict__ Wv,
                      short* __restrict__ WkT, short* __restrict__ WvT) {
    int idx = blockIdx.x * 256 + threadIdx.x;   // 0..65535
    int k = idx >> 8, n = idx & 255;
    // read coalesced in n, write transposed (L2 absorbs; tiny kernel)
    WkT[n * 256 + k] = f2bf(Wk[k * 256 + n]);
    WvT[n * 256 + k] = f2bf(Wv[k * 256 + n]);
}

// ---------------- KA: LN1 + Q projection -----------------------------------
__global__ void ln1_qproj(const float* __restrict__ tq, const float* __restrict__ Wq,
                          const float* __restrict__ bq, const float* __restrict__ g1,
                          const float* __restrict__ be1, float* __restrict__ qout) {
    __shared__ float xs[16][256];
    int r0 = blockIdx.x * 16;
    int t = threadIdx.x;
    for (int it = 0; it < 16; ++it)
        xs[it][t] = tq[(size_t)(r0 + it) * 256 + t];
    __syncthreads();
    int wv = t >> 6, ln = t & 63;
    for (int i = 0; i < 4; ++i) {
        int r = wv * 4 + i;
        float s = 0.f, ss = 0.f;
        for (int j = ln; j < 256; j += 64) { float x = xs[r][j]; s += x; ss += x * x; }
        for (int m = 1; m < 64; m <<= 1) { s += __shfl_xor(s, m); ss += __shfl_xor(ss, m); }
        float mu = s * (1.f / 256.f);
        float var = ss * (1.f / 256.f) - mu * mu;
        float rstd = rsqrtf(var + 1e-5f);
        for (int j = ln; j < 256; j += 64)
            xs[r][j] = (xs[r][j] - mu) * rstd * g1[j] + be1[j];
    }
    __syncthreads();
    float acc[16];
#pragma unroll
    for (int r = 0; r < 16; ++r) acc[r] = 0.f;
    for (int i = 0; i < 256; ++i) {
        float w = Wq[i * 256 + t];
#pragma unroll
        for (int r = 0; r < 16; ++r) acc[r] += xs[r][i] * w;
    }
    float bb = bq[t];
    for (int r = 0; r < 16; ++r) qout[(size_t)(r0 + r) * 256 + t] = acc[r] + bb;
}

// ---------------- KB: fused KV-projection + attention ----------------------
__launch_bounds__(256, 2)
__global__ void attn_fused(const float* __restrict__ sf,
                           const short* __restrict__ WkT, const short* __restrict__ WvT,
                           const float* __restrict__ bk, const float* __restrict__ bv,
                           const float* __restrict__ qws,
                           float* __restrict__ attn_out, float* __restrict__ attn_w) {
    __shared__ __align__(16) short Xs[64 * 256];   // 32 KB bf16, 16B-chunk xor swizzle
    __shared__ float qrow[256];
    __shared__ float swts[8][64];
    __shared__ float ao[256];

    int bq = blockIdx.x;
    int t = threadIdx.x;
    int w = t >> 6;
    int l = t & 63;
    int lr = l & 15, lg = l >> 4;

    const float* Xg = sf + (size_t)bq * (64 * 256);
    char* Xb = reinterpret_cast<char*>(Xs);

    // stage X -> LDS bf16 (swizzled)
    for (int it = 0; it < 16; ++it) {
        int fi = (it * 256 + t) * 4;
        int row = fi >> 8;
        int col = fi & 255;
        float4 xv = *reinterpret_cast<const float4*>(Xg + fi);
        union { short s[4]; unsigned long long u; } pk;
        pk.s[0] = f2bf(xv.x); pk.s[1] = f2bf(xv.y);
        pk.s[2] = f2bf(xv.z); pk.s[3] = f2bf(xv.w);
        int base = row * 512 + col * 2;
        base ^= (row & 7) << 4;
        *reinterpret_cast<unsigned long long*>(Xb + base) = pk.u;
    }
    qrow[t] = qws[(size_t)bq * 256 + t];
    __syncthreads();

    // MFMA: per wave, 64 output cols of K and of V (heads 2w, 2w+1)
    f32x4 ak[4][4], av[4][4];
#pragma unroll
    for (int mi = 0; mi < 4; ++mi)
#pragma unroll
        for (int ni = 0; ni < 4; ++ni) {
            ak[mi][ni] = (f32x4){0.f, 0.f, 0.f, 0.f};
            av[mi][ni] = (f32x4){0.f, 0.f, 0.f, 0.f};
        }

#pragma unroll
    for (int kk = 0; kk < 8; ++kk) {
        bf16x8 a[4];
#pragma unroll
        for (int mi = 0; mi < 4; ++mi) {
            int row = mi * 16 + lr;
            int addr = row * 512 + kk * 64 + lg * 16;
            addr ^= (row & 7) << 4;
            a[mi] = *reinterpret_cast<const bf16x8*>(Xb + addr);
        }
        bf16x8 bkf[4], bvf[4];
#pragma unroll
        for (int ni = 0; ni < 4; ++ni) {
            int col = w * 64 + ni * 16 + lr;
            int off = col * 256 + kk * 32 + lg * 8;
            bkf[ni] = *reinterpret_cast<const bf16x8*>(WkT + off);
            bvf[ni] = *reinterpret_cast<const bf16x8*>(WvT + off);
        }
#pragma unroll
        for (int mi = 0; mi < 4; ++mi)
#pragma unroll
            for (int ni = 0; ni < 4; ++ni) {
                ak[mi][ni] = __builtin_amdgcn_mfma_f32_16x16x32_bf16(a[mi], bkf[ni], ak[mi][ni], 0, 0, 0);
                av[mi][ni] = __builtin_amdgcn_mfma_f32_16x16x32_bf16(a[mi], bvf[ni], av[mi][ni], 0, 0, 0);
            }
    }

    // add biases
    float bkv[4], bvv[4];
#pragma unroll
    for (int ni = 0; ni < 4; ++ni) {
        int col = w * 64 + ni * 16 + lr;
        bkv[ni] = bk[col];
        bvv[ni] = bv[col];
    }
#pragma unroll
    for (int mi = 0; mi < 4; ++mi)
#pragma unroll
        for (int ni = 0; ni < 4; ++ni)
#pragma unroll
            for (int r = 0; r < 4; ++r) {
                ak[mi][ni][r] += bkv[ni];
                av[mi][ni][r] += bvv[ni];
            }

    const float scale = 0.17677669529663687f;  // 1/sqrt(32)
#pragma unroll
    for (int hl = 0; hl < 2; ++hl) {
        int h = w * 2 + hl;
        float q0 = qrow[h * 32 + lr];
        float q1 = qrow[h * 32 + 16 + lr];
        float sc[4][4];
#pragma unroll
        for (int mi = 0; mi < 4; ++mi)
#pragma unroll
            for (int r = 0; r < 4; ++r)
                sc[mi][r] = q0 * ak[mi][2 * hl][r] + q1 * ak[mi][2 * hl + 1][r];
        // reduce over the 16 lanes of each group (sums the 32 d-values)
#pragma unroll
        for (int m = 1; m <= 8; m <<= 1)
#pragma unroll
            for (int mi = 0; mi < 4; ++mi)
#pragma unroll
                for (int r = 0; r < 4; ++r)
                    sc[mi][r] += __shfl_xor(sc[mi][r], m);
        float mx = -1e30f;
#pragma unroll
        for (int mi = 0; mi < 4; ++mi)
#pragma unroll
            for (int r = 0; r < 4; ++r) {
                sc[mi][r] *= scale;
                mx = fmaxf(mx, sc[mi][r]);
            }
        mx = fmaxf(mx, __shfl_xor(mx, 16));
        mx = fmaxf(mx, __shfl_xor(mx, 32));
        float sm = 0.f;
#pragma unroll
        for (int mi = 0; mi < 4; ++mi)
#pragma unroll
            for (int r = 0; r < 4; ++r) {
                sc[mi][r] = __expf(sc[mi][r] - mx);
                sm += sc[mi][r];
            }
        sm += __shfl_xor(sm, 16);
        sm += __shfl_xor(sm, 32);
        float inv = 1.f / sm;
        float o0 = 0.f, o1 = 0.f;
#pragma unroll
        for (int mi = 0; mi < 4; ++mi)
#pragma unroll
            for (int r = 0; r < 4; ++r) {
                sc[mi][r] *= inv;
                o0 += sc[mi][r] * av[mi][2 * hl][r];
                o1 += sc[mi][r] * av[mi][2 * hl + 1][r];
            }
        if (lr == 0) {
#pragma unroll
            for (int mi = 0; mi < 4; ++mi)
#pragma unroll
                for (int r = 0; r < 4; ++r)
                    swts[h][mi * 16 + lg * 4 + r] = sc[mi][r];
        }
        o0 += __shfl_xor(o0, 16); o0 += __shfl_xor(o0, 32);
        o1 += __shfl_xor(o1, 16); o1 += __shfl_xor(o1, 32);
        if (lg == 0) {
            ao[h * 32 + lr] = o0;
            ao[h * 32 + 16 + lr] = o1;
        }
    }
    __syncthreads();

    int b = bq >> 11, qq = bq & 2047;
    for (int idx = t; idx < 512; idx += 256) {
        int h = idx >> 6, key = idx & 63;
        attn_w[(((size_t)b * 8 + h) * QTOT + qq) * 64 + key] = swts[h][key];
    }
    attn_out[(size_t)bq * 256 + t] = ao[t];
}

// ---------------- KC: O-proj + residual + LN2 ------------------------------
__global__ void oproj_ln2(const float* __restrict__ ain, const float* __restrict__ tq,
                          const float* __restrict__ Wo, const float* __restrict__ bo,
                          const float* __restrict__ g2, const float* __restrict__ be2,
                          float* __restrict__ xout, float* __restrict__ xnout) {
    __shared__ float as[16][256];
    __shared__ float xsh[16][256];
    int r0 = blockIdx.x * 16;
    int t = threadIdx.x;
    for (int it = 0; it < 16; ++it)
        as[it][t] = ain[(size_t)(r0 + it) * 256 + t];
    __syncthreads();
    float acc[16];
#pragma unroll
    for (int r = 0; r < 16; ++r) acc[r] = 0.f;
    for (int i = 0; i < 256; ++i) {
        float w = Wo[i * 256 + t];
#pragma unroll
        for (int r = 0; r < 16; ++r) acc[r] += as[r][i] * w;
    }
    float bb = bo[t];
    for (int r = 0; r < 16; ++r) {
        float x = tq[(size_t)(r0 + r) * 256 + t] + acc[r] + bb;
        xsh[r][t] = x;
        xout[(size_t)(r0 + r) * 256 + t] = x;
    }
    __syncthreads();
    int wv = t >> 6, ln = t & 63;
    for (int i = 0; i < 4; ++i) {
        int r = wv * 4 + i;
        float s = 0.f, ss = 0.f;
        for (int j = ln; j < 256; j += 64) { float x = xsh[r][j]; s += x; ss += x * x; }
        for (int m = 1; m < 64; m <<= 1) { s += __shfl_xor(s, m); ss += __shfl_xor(ss, m); }
        float mu = s * (1.f / 256.f);
        float var = ss * (1.f / 256.f) - mu * mu;
        float rstd = rsqrtf(var + 1e-5f);
        for (int j = ln; j < 256; j += 64)
            xnout[(size_t)(r0 + r) * 256 + j] = (xsh[r][j] - mu) * rstd * g2[j] + be2[j];
    }
}

// ---------------- KD: FFN1 + GELU ------------------------------------------
__global__ void ffn1(const float* __restrict__ xn, const float* __restrict__ W1,
                     const float* __restrict__ b1, float* __restrict__ hout) {
    __shared__ float xs[16][256];
    int r0 = blockIdx.x * 16;
    int t = threadIdx.x;
    for (int it = 0; it < 16; ++it)
        xs[it][t] = xn[(size_t)(r0 + it) * 256 + t];
    __syncthreads();
    float a0[16], a1[16], a2[16], a3[16];
#pragma unroll
    for (int r = 0; r < 16; ++r) { a0[r] = 0.f; a1[r] = 0.f; a2[r] = 0.f; a3[r] = 0.f; }
    for (int i = 0; i < 256; ++i) {
        const float* wr = W1 + (size_t)i * 1024;
        float w0 = wr[t], w1 = wr[t + 256], w2 = wr[t + 512], w3 = wr[t + 768];
#pragma unroll
        for (int r = 0; r < 16; ++r) {
            float x = xs[r][i];
            a0[r] += x * w0; a1[r] += x * w1; a2[r] += x * w2; a3[r] += x * w3;
        }
    }
    for (int j = 0; j < 4; ++j) {
        int c = t + j * 256;
        float bb = b1[c];
        for (int r = 0; r < 16; ++r) {
            float v = (j == 0 ? a0[r] : j == 1 ? a1[r] : j == 2 ? a2[r] : a3[r]) + bb;
            float g = 0.5f * v * (1.f + erff(v * 0.7071067811865475f));
            hout[(size_t)(r0 + r) * 1024 + c] = g;
        }
    }
}

// ---------------- KE: FFN2 + residual --------------------------------------
__global__ void ffn2(const float* __restrict__ hin, const float* __restrict__ x,
                     const float* __restrict__ W2, const float* __restrict__ b2,
                     float* __restrict__ out) {
    __shared__ float hs[16][1024];   // 64 KB
    int r0 = blockIdx.x * 16;
    int t = threadIdx.x;
    for (int it = 0; it < 64; ++it) {
        int flat = it * 256 + t;
        hs[flat >> 10][flat & 1023] = hin[(size_t)r0 * 1024 + flat];
    }
    __syncthreads();
    float acc[16];
#pragma unroll
    for (int r = 0; r < 16; ++r) acc[r] = 0.f;
    for (int i = 0; i < 1024; ++i) {
        float w = W2[(size_t)i * 256 + t];
#pragma unroll
        for (int r = 0; r < 16; ++r) acc[r] += hs[r][i] * w;
    }
    float bb = b2[t];
    for (int r = 0; r < 16; ++r)
        out[(size_t)(r0 + r) * 256 + t] = x[(size_t)(r0 + r) * 256 + t] + acc[r] + bb;
}

extern "C" void kernel_launch(void* const* d_in, const int* in_sizes, int n_in,
                              void* d_out, int out_size, void* d_ws, size_t ws_size,
                              hipStream_t stream) {
    const float* tq  = (const float*)d_in[0];
    const float* sf  = (const float*)d_in[1];
    const float* Wq  = (const float*)d_in[2];
    const float* bq  = (const float*)d_in[3];
    const float* Wk  = (const float*)d_in[4];
    const float* bk  = (const float*)d_in[5];
    const float* Wv  = (const float*)d_in[6];
    const float* bv  = (const float*)d_in[7];
    const float* Wo  = (const float*)d_in[8];
    const float* bo  = (const float*)d_in[9];
    const float* g1  = (const float*)d_in[10];
    const float* be1 = (const float*)d_in[11];
    const float* g2  = (const float*)d_in[12];
    const float* be2 = (const float*)d_in[13];
    const float* W1  = (const float*)d_in[14];
    const float* b1  = (const float*)d_in[15];
    const float* W2  = (const float*)d_in[16];
    const float* b2  = (const float*)d_in[17];

    char* wsb = (char*)d_ws;
    short* WkT  = (short*)(wsb + 0);
    short* WvT  = (short*)(wsb + 131072);
    float* qws  = (float*)(wsb + 262144);
    float* aows = (float*)(wsb + 4456448);
    float* xws  = (float*)(wsb + 8650752);
    float* xnws = (float*)(wsb + 12845056);
    float* hws  = (float*)(wsb + 17039360);

    float* outp   = (float*)d_out;
    float* attnwp = (float*)d_out + 1048576;

    wconv<<<256, 256, 0, stream>>>(Wk, Wv, WkT, WvT);
    ln1_qproj<<<256, 256, 0, stream>>>(tq, Wq, bq, g1, be1, qws);
    attn_fused<<<4096, 256, 0, stream>>>(sf, WkT, WvT, bk, bv, qws, aows, attnwp);
    oproj_ln2<<<256, 256, 0, stream>>>(aows, tq, Wo, bo, g2, be2, xws, xnws);
    ffn1<<<256, 256, 0, stream>>>(xnws, W1, b1, hws);
    ffn2<<<256, 256, 0, stream>>>(hws, xws, W2, b2, outp);
}

// Round 2
// 324.048 us; speedup vs baseline: 1.2670x; 1.2670x over previous
//
#include <hip/hip_runtime.h>
#include <hip/hip_bf16.h>
#include <math.h>

#define DMODEL 256
#define NHEADS 8
#define DK 32
#define NKEYS 64
#define FFN 1024
#define NROWS 4096   // B*Q
#define QTOT 2048

using bf16x8 = __attribute__((ext_vector_type(8))) short;
using f32x4  = __attribute__((ext_vector_type(4))) float;

static __device__ __forceinline__ short f2bf(float f) {
    union { float f; unsigned u; } v; v.f = f;
    unsigned r = v.u + 0x7fffu + ((v.u >> 16) & 1u);
    return (short)(r >> 16);
}

// ---------------- K0: weight convert into MFMA-fragment-packed bf16 --------
// Packed layout: chunk ci = ((cb*8 + kk)*64 + l), 16B each (8 bf16).
// For lane l (lr=l&15, lg=l>>4): elems e=0..7 = W[k = kk*32+lg*8+e][n = cb*16+lr].
// A wave's B-fragment load becomes base + l*16: one coalesced 1KB burst.
__global__ void wconv(const float* __restrict__ Wk, const float* __restrict__ Wv,
                      short* __restrict__ WkP, short* __restrict__ WvP) {
    int ci = blockIdx.x * 256 + threadIdx.x;   // 0..8191
    int cb = ci >> 9;
    int kk = (ci >> 6) & 7;
    int l  = ci & 63;
    int lr = l & 15, lg = l >> 4;
    int n = cb * 16 + lr;
    int kb = kk * 32 + lg * 8;
    short pk[8], pv[8];
#pragma unroll
    for (int e = 0; e < 8; ++e) {
        pk[e] = f2bf(Wk[(size_t)(kb + e) * 256 + n]);
        pv[e] = f2bf(Wv[(size_t)(kb + e) * 256 + n]);
    }
    *reinterpret_cast<bf16x8*>(WkP + (size_t)ci * 8) = *reinterpret_cast<bf16x8*>(pk);
    *reinterpret_cast<bf16x8*>(WvP + (size_t)ci * 8) = *reinterpret_cast<bf16x8*>(pv);
}

// ---------------- KA: LN1 + Q projection (8-row tiles) ---------------------
__global__ void ln1_qproj(const float* __restrict__ tq, const float* __restrict__ Wq,
                          const float* __restrict__ bq, const float* __restrict__ g1,
                          const float* __restrict__ be1, float* __restrict__ qout) {
    __shared__ float xs[8][256];
    int r0 = blockIdx.x * 8;
    int t = threadIdx.x;
    for (int it = 0; it < 8; ++it)
        xs[it][t] = tq[(size_t)(r0 + it) * 256 + t];
    __syncthreads();
    int wv = t >> 6, ln = t & 63;
    for (int i = 0; i < 2; ++i) {
        int r = wv * 2 + i;
        float s = 0.f, ss = 0.f;
        for (int j = ln; j < 256; j += 64) { float x = xs[r][j]; s += x; ss += x * x; }
        for (int m = 1; m < 64; m <<= 1) { s += __shfl_xor(s, m); ss += __shfl_xor(ss, m); }
        float mu = s * (1.f / 256.f);
        float var = ss * (1.f / 256.f) - mu * mu;
        float rstd = rsqrtf(var + 1e-5f);
        for (int j = ln; j < 256; j += 64)
            xs[r][j] = (xs[r][j] - mu) * rstd * g1[j] + be1[j];
    }
    __syncthreads();
    float acc[8];
#pragma unroll
    for (int r = 0; r < 8; ++r) acc[r] = 0.f;
    for (int i = 0; i < 256; ++i) {
        float w = Wq[i * 256 + t];
#pragma unroll
        for (int r = 0; r < 8; ++r) acc[r] += xs[r][i] * w;
    }
    float bb = bq[t];
    for (int r = 0; r < 8; ++r) qout[(size_t)(r0 + r) * 256 + t] = acc[r] + bb;
}

// ---------------- KB: fused KV-projection + attention ----------------------
__launch_bounds__(256, 2)
__global__ void attn_fused(const float* __restrict__ sf,
                           const short* __restrict__ WkP, const short* __restrict__ WvP,
                           const float* __restrict__ bk, const float* __restrict__ bv,
                           const float* __restrict__ qws,
                           float* __restrict__ attn_out, float* __restrict__ attn_w) {
    __shared__ __align__(16) short Xs[64 * 256];   // 32 KB bf16, 16B-chunk xor swizzle
    __shared__ float qrow[256];
    __shared__ float swts[8][64];
    __shared__ float ao[256];

    int bq = blockIdx.x;
    int t = threadIdx.x;
    int w = t >> 6;
    int l = t & 63;
    int lr = l & 15, lg = l >> 4;

    const float* Xg = sf + (size_t)bq * (64 * 256);
    char* Xb = reinterpret_cast<char*>(Xs);

    qrow[t] = qws[(size_t)bq * 256 + t];

    // stage X -> LDS bf16 (swizzled), 8 floats -> one b128 write per iter
#pragma unroll
    for (int it = 0; it < 8; ++it) {
        int flat = it * 256 + t;       // 8-float chunk id
        int f0 = flat * 8;
        int row = f0 >> 8;
        int col = f0 & 255;
        float4 xa = *reinterpret_cast<const float4*>(Xg + f0);
        float4 xb = *reinterpret_cast<const float4*>(Xg + f0 + 4);
        short pk[8];
        pk[0] = f2bf(xa.x); pk[1] = f2bf(xa.y); pk[2] = f2bf(xa.z); pk[3] = f2bf(xa.w);
        pk[4] = f2bf(xb.x); pk[5] = f2bf(xb.y); pk[6] = f2bf(xb.z); pk[7] = f2bf(xb.w);
        int base = row * 512 + col * 2;
        base ^= (row & 7) << 4;
        *reinterpret_cast<bf16x8*>(Xb + base) = *reinterpret_cast<bf16x8*>(pk);
    }
    __syncthreads();

    // MFMA: per wave, 64 output cols of K and of V (heads 2w, 2w+1)
    f32x4 ak[4][4], av[4][4];
#pragma unroll
    for (int mi = 0; mi < 4; ++mi)
#pragma unroll
        for (int ni = 0; ni < 4; ++ni) {
            ak[mi][ni] = (f32x4){0.f, 0.f, 0.f, 0.f};
            av[mi][ni] = (f32x4){0.f, 0.f, 0.f, 0.f};
        }

    // per-thread packed-weight base: wave w covers col-blocks cb = w*4 + ni
    const short* pkK = WkP + ((size_t)w * 4 * 8 * 64 + l) * 8;
    const short* pkV = WvP + ((size_t)w * 4 * 8 * 64 + l) * 8;

#pragma unroll
    for (int kk = 0; kk < 8; ++kk) {
        bf16x8 a[4];
#pragma unroll
        for (int mi = 0; mi < 4; ++mi) {
            int row = mi * 16 + lr;
            int addr = row * 512 + kk * 64 + lg * 16;
            addr ^= (row & 7) << 4;
            a[mi] = *reinterpret_cast<const bf16x8*>(Xb + addr);
        }
        bf16x8 bkf[4], bvf[4];
#pragma unroll
        for (int ni = 0; ni < 4; ++ni) {
            int off = (ni * 8 + kk) * 64 * 8;   // shorts
            bkf[ni] = *reinterpret_cast<const bf16x8*>(pkK + off);
            bvf[ni] = *reinterpret_cast<const bf16x8*>(pkV + off);
        }
#pragma unroll
        for (int mi = 0; mi < 4; ++mi)
#pragma unroll
            for (int ni = 0; ni < 4; ++ni) {
                ak[mi][ni] = __builtin_amdgcn_mfma_f32_16x16x32_bf16(a[mi], bkf[ni], ak[mi][ni], 0, 0, 0);
                av[mi][ni] = __builtin_amdgcn_mfma_f32_16x16x32_bf16(a[mi], bvf[ni], av[mi][ni], 0, 0, 0);
            }
    }

    // add biases
    float bkv[4], bvv[4];
#pragma unroll
    for (int ni = 0; ni < 4; ++ni) {
        int col = w * 64 + ni * 16 + lr;
        bkv[ni] = bk[col];
        bvv[ni] = bv[col];
    }
#pragma unroll
    for (int mi = 0; mi < 4; ++mi)
#pragma unroll
        for (int ni = 0; ni < 4; ++ni)
#pragma unroll
            for (int r = 0; r < 4; ++r) {
                ak[mi][ni][r] += bkv[ni];
                av[mi][ni][r] += bvv[ni];
            }

    const float scale = 0.17677669529663687f;  // 1/sqrt(32)
#pragma unroll
    for (int hl = 0; hl < 2; ++hl) {
        int h = w * 2 + hl;
        float q0 = qrow[h * 32 + lr];
        float q1 = qrow[h * 32 + 16 + lr];
        float sc[4][4];
#pragma unroll
        for (int mi = 0; mi < 4; ++mi)
#pragma unroll
            for (int r = 0; r < 4; ++r)
                sc[mi][r] = q0 * ak[mi][2 * hl][r] + q1 * ak[mi][2 * hl + 1][r];
        // reduce over the 16 lanes of each group (sums the 32 d-values)
#pragma unroll
        for (int m = 1; m <= 8; m <<= 1)
#pragma unroll
            for (int mi = 0; mi < 4; ++mi)
#pragma unroll
                for (int r = 0; r < 4; ++r)
                    sc[mi][r] += __shfl_xor(sc[mi][r], m);
        float mx = -1e30f;
#pragma unroll
        for (int mi = 0; mi < 4; ++mi)
#pragma unroll
            for (int r = 0; r < 4; ++r) {
                sc[mi][r] *= scale;
                mx = fmaxf(mx, sc[mi][r]);
            }
        mx = fmaxf(mx, __shfl_xor(mx, 16));
        mx = fmaxf(mx, __shfl_xor(mx, 32));
        float sm = 0.f;
#pragma unroll
        for (int mi = 0; mi < 4; ++mi)
#pragma unroll
            for (int r = 0; r < 4; ++r) {
                sc[mi][r] = __expf(sc[mi][r] - mx);
                sm += sc[mi][r];
            }
        sm += __shfl_xor(sm, 16);
        sm += __shfl_xor(sm, 32);
        float inv = 1.f / sm;
        float o0 = 0.f, o1 = 0.f;
#pragma unroll
        for (int mi = 0; mi < 4; ++mi)
#pragma unroll
            for (int r = 0; r < 4; ++r) {
                sc[mi][r] *= inv;
                o0 += sc[mi][r] * av[mi][2 * hl][r];
                o1 += sc[mi][r] * av[mi][2 * hl + 1][r];
            }
        if (lr == 0) {
#pragma unroll
            for (int mi = 0; mi < 4; ++mi)
#pragma unroll
                for (int r = 0; r < 4; ++r)
                    swts[h][mi * 16 + lg * 4 + r] = sc[mi][r];
        }
        o0 += __shfl_xor(o0, 16); o0 += __shfl_xor(o0, 32);
        o1 += __shfl_xor(o1, 16); o1 += __shfl_xor(o1, 32);
        if (lg == 0) {
            ao[h * 32 + lr] = o0;
            ao[h * 32 + 16 + lr] = o1;
        }
    }
    __syncthreads();

    int b = bq >> 11, qq = bq & 2047;
    for (int idx = t; idx < 512; idx += 256) {
        int h = idx >> 6, key = idx & 63;
        attn_w[(((size_t)b * 8 + h) * QTOT + qq) * 64 + key] = swts[h][key];
    }
    attn_out[(size_t)bq * 256 + t] = ao[t];
}

// ---------------- KC: O-proj + residual + LN2 (8-row tiles) ----------------
__global__ void oproj_ln2(const float* __restrict__ ain, const float* __restrict__ tq,
                          const float* __restrict__ Wo, const float* __restrict__ bo,
                          const float* __restrict__ g2, const float* __restrict__ be2,
                          float* __restrict__ xout, float* __restrict__ xnout) {
    __shared__ float as[8][256];
    __shared__ float xsh[8][256];
    int r0 = blockIdx.x * 8;
    int t = threadIdx.x;
    for (int it = 0; it < 8; ++it)
        as[it][t] = ain[(size_t)(r0 + it) * 256 + t];
    __syncthreads();
    float acc[8];
#pragma unroll
    for (int r = 0; r < 8; ++r) acc[r] = 0.f;
    for (int i = 0; i < 256; ++i) {
        float w = Wo[i * 256 + t];
#pragma unroll
        for (int r = 0; r < 8; ++r) acc[r] += as[r][i] * w;
    }
    float bb = bo[t];
    for (int r = 0; r < 8; ++r) {
        float x = tq[(size_t)(r0 + r) * 256 + t] + acc[r] + bb;
        xsh[r][t] = x;
        xout[(size_t)(r0 + r) * 256 + t] = x;
    }
    __syncthreads();
    int wv = t >> 6, ln = t & 63;
    for (int i = 0; i < 2; ++i) {
        int r = wv * 2 + i;
        float s = 0.f, ss = 0.f;
        for (int j = ln; j < 256; j += 64) { float x = xsh[r][j]; s += x; ss += x * x; }
        for (int m = 1; m < 64; m <<= 1) { s += __shfl_xor(s, m); ss += __shfl_xor(ss, m); }
        float mu = s * (1.f / 256.f);
        float var = ss * (1.f / 256.f) - mu * mu;
        float rstd = rsqrtf(var + 1e-5f);
        for (int j = ln; j < 256; j += 64)
            xnout[(size_t)(r0 + r) * 256 + j] = (xsh[r][j] - mu) * rstd * g2[j] + be2[j];
    }
}

// ---------------- KD: FFN1 + GELU (8-row tiles) ----------------------------
__global__ void ffn1(const float* __restrict__ xn, const float* __restrict__ W1,
                     const float* __restrict__ b1, float* __restrict__ hout) {
    __shared__ float xs[8][256];
    int r0 = blockIdx.x * 8;
    int t = threadIdx.x;
    for (int it = 0; it < 8; ++it)
        xs[it][t] = xn[(size_t)(r0 + it) * 256 + t];
    __syncthreads();
    float a0[8], a1[8], a2[8], a3[8];
#pragma unroll
    for (int r = 0; r < 8; ++r) { a0[r] = 0.f; a1[r] = 0.f; a2[r] = 0.f; a3[r] = 0.f; }
    for (int i = 0; i < 256; ++i) {
        const float* wr = W1 + (size_t)i * 1024;
        float w0 = wr[t], w1 = wr[t + 256], w2 = wr[t + 512], w3 = wr[t + 768];
#pragma unroll
        for (int r = 0; r < 8; ++r) {
            float x = xs[r][i];
            a0[r] += x * w0; a1[r] += x * w1; a2[r] += x * w2; a3[r] += x * w3;
        }
    }
    for (int j = 0; j < 4; ++j) {
        int c = t + j * 256;
        float bb = b1[c];
        for (int r = 0; r < 8; ++r) {
            float v = (j == 0 ? a0[r] : j == 1 ? a1[r] : j == 2 ? a2[r] : a3[r]) + bb;
            float g = 0.5f * v * (1.f + erff(v * 0.7071067811865475f));
            hout[(size_t)(r0 + r) * 1024 + c] = g;
        }
    }
}

// ---------------- KE: FFN2 + residual (8-row tiles) ------------------------
__global__ void ffn2(const float* __restrict__ hin, const float* __restrict__ x,
                     const float* __restrict__ W2, const float* __restrict__ b2,
                     float* __restrict__ out) {
    __shared__ float hs[8][1024];   // 32 KB
    int r0 = blockIdx.x * 8;
    int t = threadIdx.x;
    for (int it = 0; it < 32; ++it) {
        int flat = it * 256 + t;
        hs[flat >> 10][flat & 1023] = hin[(size_t)r0 * 1024 + flat];
    }
    __syncthreads();
    float acc[8];
#pragma unroll
    for (int r = 0; r < 8; ++r) acc[r] = 0.f;
    for (int i = 0; i < 1024; ++i) {
        float w = W2[(size_t)i * 256 + t];
#pragma unroll
        for (int r = 0; r < 8; ++r) acc[r] += hs[r][i] * w;
    }
    float bb = b2[t];
    for (int r = 0; r < 8; ++r)
        out[(size_t)(r0 + r) * 256 + t] = x[(size_t)(r0 + r) * 256 + t] + acc[r] + bb;
}

extern "C" void kernel_launch(void* const* d_in, const int* in_sizes, int n_in,
                              void* d_out, int out_size, void* d_ws, size_t ws_size,
                              hipStream_t stream) {
    const float* tq  = (const float*)d_in[0];
    const float* sf  = (const float*)d_in[1];
    const float* Wq  = (const float*)d_in[2];
    const float* bq  = (const float*)d_in[3];
    const float* Wk  = (const float*)d_in[4];
    const float* bk  = (const float*)d_in[5];
    const float* Wv  = (const float*)d_in[6];
    const float* bv  = (const float*)d_in[7];
    const float* Wo  = (const float*)d_in[8];
    const float* bo  = (const float*)d_in[9];
    const float* g1  = (const float*)d_in[10];
    const float* be1 = (const float*)d_in[11];
    const float* g2  = (const float*)d_in[12];
    const float* be2 = (const float*)d_in[13];
    const float* W1  = (const float*)d_in[14];
    const float* b1  = (const float*)d_in[15];
    const float* W2  = (const float*)d_in[16];
    const float* b2  = (const float*)d_in[17];

    char* wsb = (char*)d_ws;
    short* WkP  = (short*)(wsb + 0);
    short* WvP  = (short*)(wsb + 131072);
    float* qws  = (float*)(wsb + 262144);
    float* aows = (float*)(wsb + 4456448);
    float* xws  = (float*)(wsb + 8650752);
    float* xnws = (float*)(wsb + 12845056);
    float* hws  = (float*)(wsb + 17039360);

    float* outp   = (float*)d_out;
    float* attnwp = (float*)d_out + 1048576;

    wconv<<<32, 256, 0, stream>>>(Wk, Wv, WkP, WvP);
    ln1_qproj<<<512, 256, 0, stream>>>(tq, Wq, bq, g1, be1, qws);
    attn_fused<<<4096, 256, 0, stream>>>(sf, WkP, WvP, bk, bv, qws, aows, attnwp);
    oproj_ln2<<<512, 256, 0, stream>>>(aows, tq, Wo, bo, g2, be2, xws, xnws);
    ffn1<<<512, 256, 0, stream>>>(xnws, W1, b1, hws);
    ffn2<<<512, 256, 0, stream>>>(hws, xws, W2, b2, outp);
}

// Round 3
// 189.749 us; speedup vs baseline: 2.1637x; 1.7078x over previous
//
#include <hip/hip_runtime.h>
#include <math.h>

#define QTOT 2048

using bf16x8 = __attribute__((ext_vector_type(8))) short;
using f32x4  = __attribute__((ext_vector_type(4))) float;

static __device__ __forceinline__ short f2bf(float f) {
    union { float f; unsigned u; } v; v.f = f;
    unsigned r = v.u + 0x7fffu + ((v.u >> 16) & 1u);
    return (short)(r >> 16);
}
static __device__ __forceinline__ unsigned cvt_pk(float a, float b) {
    unsigned r;
    asm("v_cvt_pk_bf16_f32 %0, %1, %2" : "=v"(r) : "v"(a), "v"(b));
    return r;
}
static __device__ __forceinline__ bf16x8 pack8(float a0, float a1, float a2, float a3,
                                               float a4, float a5, float a6, float a7) {
    union { unsigned u[4]; bf16x8 v; } z;
    z.u[0] = cvt_pk(a0, a1); z.u[1] = cvt_pk(a2, a3);
    z.u[2] = cvt_pk(a4, a5); z.u[3] = cvt_pk(a6, a7);
    return z.v;
}

// ---------------- K1: pack all weights into MFMA B-fragment order ----------
// Fragment chunk ci = (cb*KK + kk)*64 + l ; elem e = B[k = kk*32+(l>>4)*8+e][n = cb*16+(l&15)]
// normal: B[k][n] = W[k*N + n] ; transposed (Wk): B[k][n] = W[n*256 + k]
__global__ void wconv(const float* __restrict__ Wq, const float* __restrict__ Wk,
                      const float* __restrict__ Wo, const float* __restrict__ Wv,
                      const float* __restrict__ W1, const float* __restrict__ W2,
                      short* __restrict__ WqP, short* __restrict__ WkP,
                      short* __restrict__ WoP, short* __restrict__ WvP,
                      short* __restrict__ W1P, short* __restrict__ W2P) {
    int b = blockIdx.x, t = threadIdx.x;
    const float* W; short* P; int N, KK, ci; bool tr = false;
    if (b < 32)       { W = Wq; P = WqP; N = 256;  KK = 8;  ci = b * 256 + t; }
    else if (b < 64)  { W = Wk; P = WkP; N = 256;  KK = 8;  ci = (b - 32) * 256 + t; tr = true; }
    else if (b < 96)  { W = Wo; P = WoP; N = 256;  KK = 8;  ci = (b - 64) * 256 + t; }
    else if (b < 128) { W = Wv; P = WvP; N = 256;  KK = 8;  ci = (b - 96) * 256 + t; }
    else if (b < 256) { W = W1; P = W1P; N = 1024; KK = 8;  ci = (b - 128) * 256 + t; }
    else              { W = W2; P = W2P; N = 256;  KK = 32; ci = (b - 256) * 256 + t; }
    int cb = ci / (KK * 64);
    int rem = ci - cb * (KK * 64);
    int kk = rem >> 6, l = rem & 63;
    int lr = l & 15, lg = l >> 4;
    int n = cb * 16 + lr, k0 = kk * 32 + lg * 8;
    short pk[8];
    if (!tr) {
#pragma unroll
        for (int e = 0; e < 8; ++e) pk[e] = f2bf(W[(size_t)(k0 + e) * N + n]);
    } else {
#pragma unroll
        for (int e = 0; e < 8; ++e) pk[e] = f2bf(W[(size_t)n * 256 + (k0 + e)]);
    }
    *reinterpret_cast<bf16x8*>(P + (size_t)ci * 8) = *reinterpret_cast<bf16x8*>(pk);
}

// ---------------- K2: LN1 + Q-proj + z = per-head Wk^T q (MFMA) ------------
__global__ void ln1z(const float* __restrict__ tq, const short* __restrict__ WqP,
                     const float* __restrict__ bq, const float* __restrict__ g1,
                     const float* __restrict__ be1, const short* __restrict__ WkP,
                     const float* __restrict__ bk, short* __restrict__ zf,
                     float* __restrict__ sbg) {
    __shared__ float xs[8 * 260];
    __shared__ float qs[8 * 260];
    int r0 = blockIdx.x * 8, t = threadIdx.x;
    int w = t >> 6, l = t & 63, lr = l & 15, lg = l >> 4;
#pragma unroll
    for (int it = 0; it < 8; ++it) xs[it * 260 + t] = tq[(size_t)(r0 + it) * 256 + t];
    __syncthreads();
#pragma unroll
    for (int i = 0; i < 2; ++i) {
        int r = w * 2 + i;
        float s = 0.f, s2 = 0.f;
        for (int j = l; j < 256; j += 64) { float x = xs[r * 260 + j]; s += x; s2 += x * x; }
#pragma unroll
        for (int m = 1; m < 64; m <<= 1) { s += __shfl_xor(s, m); s2 += __shfl_xor(s2, m); }
        float mu = s * (1.f / 256.f);
        float var = s2 * (1.f / 256.f) - mu * mu;
        float rstd = rsqrtf(var + 1e-5f);
        for (int j = l; j < 256; j += 64)
            xs[r * 260 + j] = (xs[r * 260 + j] - mu) * rstd * g1[j] + be1[j];
    }
    __syncthreads();
    // qproj: M=16 (rows 0..7 valid), N=256, K=256
    f32x4 cq[4];
#pragma unroll
    for (int ni = 0; ni < 4; ++ni) cq[ni] = (f32x4){0.f, 0.f, 0.f, 0.f};
#pragma unroll
    for (int kk = 0; kk < 8; ++kk) {
        bf16x8 af = {0, 0, 0, 0, 0, 0, 0, 0};
        if (lr < 8) {
            const float* xp = &xs[lr * 260 + kk * 32 + lg * 8];
            af = pack8(xp[0], xp[1], xp[2], xp[3], xp[4], xp[5], xp[6], xp[7]);
        }
#pragma unroll
        for (int ni = 0; ni < 4; ++ni) {
            bf16x8 bf = *reinterpret_cast<const bf16x8*>(WqP + ((size_t)((w * 4 + ni) * 8 + kk) * 64 + l) * 8);
            cq[ni] = __builtin_amdgcn_mfma_f32_16x16x32_bf16(af, bf, cq[ni], 0, 0, 0);
        }
    }
    if (lg < 2) {
#pragma unroll
        for (int ni = 0; ni < 4; ++ni)
#pragma unroll
            for (int r = 0; r < 4; ++r) {
                int row = lg * 4 + r, col = (w * 4 + ni) * 16 + lr;
                qs[row * 260 + col] = cq[ni][r] + bq[col];
            }
    }
    __syncthreads();
    if (t < 64) {
        int r = t >> 3, h = t & 7;
        float s = 0.f;
        for (int d = 0; d < 32; ++d) s += qs[r * 260 + h * 32 + d] * bk[h * 32 + d];
        sbg[(size_t)(r0 + r) * 8 + h] = s;
    }
    // z-GEMM: M=64 rows = (r*8+h); A''[r*8+h][j] = (j>>5==h) ? q[r][j] : 0 ; B = Wk^T
    f32x4 cz[4][4];
#pragma unroll
    for (int mi = 0; mi < 4; ++mi)
#pragma unroll
        for (int ni = 0; ni < 4; ++ni) cz[mi][ni] = (f32x4){0.f, 0.f, 0.f, 0.f};
#pragma unroll
    for (int kk = 0; kk < 8; ++kk) {
        bf16x8 am[4];
#pragma unroll
        for (int mi = 0; mi < 4; ++mi) {
            bf16x8 z = {0, 0, 0, 0, 0, 0, 0, 0};
            if ((lr & 7) == kk) {
                int rr = mi * 2 + (lr >> 3);
                const float* qp = &qs[rr * 260 + kk * 32 + lg * 8];
                z = pack8(qp[0], qp[1], qp[2], qp[3], qp[4], qp[5], qp[6], qp[7]);
            }
            am[mi] = z;
        }
#pragma unroll
        for (int ni = 0; ni < 4; ++ni) {
            bf16x8 bf = *reinterpret_cast<const bf16x8*>(WkP + ((size_t)((w * 4 + ni) * 8 + kk) * 64 + l) * 8);
#pragma unroll
            for (int mi = 0; mi < 4; ++mi)
                cz[mi][ni] = __builtin_amdgcn_mfma_f32_16x16x32_bf16(am[mi], bf, cz[mi][ni], 0, 0, 0);
        }
    }
    // store z in attn B-frag order: zf[row][ (i>>3)*64 + h*8 + (i&7) ]
#pragma unroll
    for (int mi = 0; mi < 4; ++mi)
#pragma unroll
        for (int ni = 0; ni < 4; ++ni)
#pragma unroll
            for (int r = 0; r < 4; ++r) {
                int mrow = mi * 16 + lg * 4 + r;
                int rr = mrow >> 3, hh = mrow & 7;
                int i = (w * 4 + ni) * 16 + lr;
                zf[(size_t)(r0 + rr) * 2048 + (i >> 3) * 64 + hh * 8 + (i & 7)] = f2bf(cz[mi][ni][r]);
            }
}

// ---------------- K3: attention per (b,q): scores, softmax, u=P@X, out=u@Wv -
__launch_bounds__(256, 3)
__global__ void attn(const float* __restrict__ sf, const short* __restrict__ zf,
                     const float* __restrict__ sbg, const short* __restrict__ WvP,
                     const float* __restrict__ bv, short* __restrict__ aob,
                     float* __restrict__ attn_w) {
    __shared__ float ss[64 * 9];
    __shared__ float ps[64 * 8];
    __shared__ float us[8 * 272];
    int bq = blockIdx.x, t = threadIdx.x;
    int w = t >> 6, l = t & 63, lr = l & 15, lg = l >> 4;
    const float* Xg = sf + (size_t)bq * 16384;

    bf16x8 zfr[8];
#pragma unroll
    for (int kk = 0; kk < 8; ++kk) {
        bf16x8 z = {0, 0, 0, 0, 0, 0, 0, 0};
        if (lr < 8)
            z = *reinterpret_cast<const bf16x8*>(zf + (size_t)bq * 2048 + ((size_t)((kk * 4 + lg) * 8 + lr)) * 8);
        zfr[kk] = z;
    }
    float sbv = sbg[(size_t)bq * 8 + (lr & 7)];

    // scores: S(64key x 8h) = X @ z ; A-frags straight from global
    f32x4 cs = {0.f, 0.f, 0.f, 0.f};
    const float* Xr = Xg + (16 * w + lr) * 256;
#pragma unroll
    for (int kk = 0; kk < 8; ++kk) {
        float4 xa = *reinterpret_cast<const float4*>(Xr + kk * 32 + lg * 8);
        float4 xb = *reinterpret_cast<const float4*>(Xr + kk * 32 + lg * 8 + 4);
        bf16x8 af = pack8(xa.x, xa.y, xa.z, xa.w, xb.x, xb.y, xb.z, xb.w);
        cs = __builtin_amdgcn_mfma_f32_16x16x32_bf16(af, zfr[kk], cs, 0, 0, 0);
    }
    const float scale = 0.17677669529663687f;  // 1/sqrt(32)
    if (lr < 8) {
#pragma unroll
        for (int r = 0; r < 4; ++r)
            ss[(16 * w + lg * 4 + r) * 9 + lr] = (cs[r] + sbv) * scale;
    }
    __syncthreads();

    // softmax: wave w handles heads 2w, 2w+1; lane = key
    int b = bq >> 11, qq = bq & 2047;
#pragma unroll
    for (int hi = 0; hi < 2; ++hi) {
        int hh = w * 2 + hi;
        float s = ss[l * 9 + hh];
        float m = s;
#pragma unroll
        for (int off = 1; off < 64; off <<= 1) m = fmaxf(m, __shfl_xor(m, off));
        float p = __expf(s - m);
        float sm = p;
#pragma unroll
        for (int off = 1; off < 64; off <<= 1) sm += __shfl_xor(sm, off);
        float P = p / sm;
        ps[l * 8 + hh] = P;
        attn_w[(((size_t)b * 8 + hh) * QTOT + qq) * 64 + l] = P;
    }
    __syncthreads();

    // u-GEMM: u(8h x 256c) = P @ X ; K=64 (2 steps); B from global X (transposed gather)
    bf16x8 pa[2];
#pragma unroll
    for (int k2 = 0; k2 < 2; ++k2) {
        bf16x8 z = {0, 0, 0, 0, 0, 0, 0, 0};
        if (lr < 8) {
            int kb = k2 * 32 + lg * 8;
            z = pack8(ps[(kb + 0) * 8 + lr], ps[(kb + 1) * 8 + lr], ps[(kb + 2) * 8 + lr],
                      ps[(kb + 3) * 8 + lr], ps[(kb + 4) * 8 + lr], ps[(kb + 5) * 8 + lr],
                      ps[(kb + 6) * 8 + lr], ps[(kb + 7) * 8 + lr]);
        }
        pa[k2] = z;
    }
    f32x4 cu[4];
#pragma unroll
    for (int ni = 0; ni < 4; ++ni) cu[ni] = (f32x4){0.f, 0.f, 0.f, 0.f};
#pragma unroll
    for (int ni = 0; ni < 4; ++ni) {
        int c = (w * 4 + ni) * 16 + lr;
#pragma unroll
        for (int k2 = 0; k2 < 2; ++k2) {
            int kb = k2 * 32 + lg * 8;
            bf16x8 xb = pack8(Xg[(kb + 0) * 256 + c], Xg[(kb + 1) * 256 + c],
                              Xg[(kb + 2) * 256 + c], Xg[(kb + 3) * 256 + c],
                              Xg[(kb + 4) * 256 + c], Xg[(kb + 5) * 256 + c],
                              Xg[(kb + 6) * 256 + c], Xg[(kb + 7) * 256 + c]);
            cu[ni] = __builtin_amdgcn_mfma_f32_16x16x32_bf16(pa[k2], xb, cu[ni], 0, 0, 0);
        }
    }
    if (lg < 2) {
#pragma unroll
        for (int ni = 0; ni < 4; ++ni)
#pragma unroll
            for (int r = 0; r < 4; ++r)
                us[(lg * 4 + r) * 272 + (w * 4 + ni) * 16 + lr] = cu[ni][r];
    }
    __syncthreads();

    // out-GEMM: C(8h x 256j) = u @ Wv ; keep block-diagonal h == j>>5
    f32x4 co[4];
#pragma unroll
    for (int ni = 0; ni < 4; ++ni) co[ni] = (f32x4){0.f, 0.f, 0.f, 0.f};
#pragma unroll
    for (int kk = 0; kk < 8; ++kk) {
        bf16x8 ua = {0, 0, 0, 0, 0, 0, 0, 0};
        if (lr < 8) {
            const float* up = &us[lr * 272 + kk * 32 + lg * 8];
            float4 u0 = *reinterpret_cast<const float4*>(up);
            float4 u1 = *reinterpret_cast<const float4*>(up + 4);
            ua = pack8(u0.x, u0.y, u0.z, u0.w, u1.x, u1.y, u1.z, u1.w);
        }
#pragma unroll
        for (int ni = 0; ni < 4; ++ni) {
            bf16x8 bf = *reinterpret_cast<const bf16x8*>(WvP + ((size_t)((w * 4 + ni) * 8 + kk) * 64 + l) * 8);
            co[ni] = __builtin_amdgcn_mfma_f32_16x16x32_bf16(ua, bf, co[ni], 0, 0, 0);
        }
    }
#pragma unroll
    for (int ni = 0; ni < 4; ++ni) {
        int j = (w * 4 + ni) * 16 + lr;
        int h = j >> 5;
        if ((h >> 2) == lg) {
            float v = co[ni][h & 3] + bv[j];
            aob[(size_t)bq * 256 + j] = f2bf(v);
        }
    }
}

// ---------------- K4: O-proj + residual + LN2 (MFMA, 16-row blocks) --------
__global__ void oproj(const short* __restrict__ aob, const float* __restrict__ tq,
                      const short* __restrict__ WoP, const float* __restrict__ bo,
                      const float* __restrict__ g2, const float* __restrict__ be2,
                      float* __restrict__ xout, short* __restrict__ xnb) {
    __shared__ float xsh[16 * 260];
    int r0 = blockIdx.x * 16, t = threadIdx.x;
    int w = t >> 6, l = t & 63, lr = l & 15, lg = l >> 4;
    f32x4 c[4];
#pragma unroll
    for (int ni = 0; ni < 4; ++ni) c[ni] = (f32x4){0.f, 0.f, 0.f, 0.f};
#pragma unroll
    for (int kk = 0; kk < 8; ++kk) {
        bf16x8 af = *reinterpret_cast<const bf16x8*>(aob + (size_t)(r0 + lr) * 256 + kk * 32 + lg * 8);
#pragma unroll
        for (int ni = 0; ni < 4; ++ni) {
            bf16x8 bf = *reinterpret_cast<const bf16x8*>(WoP + ((size_t)((w * 4 + ni) * 8 + kk) * 64 + l) * 8);
            c[ni] = __builtin_amdgcn_mfma_f32_16x16x32_bf16(af, bf, c[ni], 0, 0, 0);
        }
    }
#pragma unroll
    for (int ni = 0; ni < 4; ++ni) {
        int col = (w * 4 + ni) * 16 + lr;
        float bb = bo[col];
#pragma unroll
        for (int r = 0; r < 4; ++r) {
            int row = lg * 4 + r;
            float x = tq[(size_t)(r0 + row) * 256 + col] + c[ni][r] + bb;
            xsh[row * 260 + col] = x;
            xout[(size_t)(r0 + row) * 256 + col] = x;
        }
    }
    __syncthreads();
#pragma unroll
    for (int i = 0; i < 4; ++i) {
        int r = w * 4 + i;
        float s = 0.f, s2 = 0.f;
        for (int j = l; j < 256; j += 64) { float x = xsh[r * 260 + j]; s += x; s2 += x * x; }
#pragma unroll
        for (int m = 1; m < 64; m <<= 1) { s += __shfl_xor(s, m); s2 += __shfl_xor(s2, m); }
        float mu = s * (1.f / 256.f);
        float var = s2 * (1.f / 256.f) - mu * mu;
        float rstd = rsqrtf(var + 1e-5f);
        for (int j = l; j < 256; j += 64)
            xnb[(size_t)(r0 + r) * 256 + j] = f2bf((xsh[r * 260 + j] - mu) * rstd * g2[j] + be2[j]);
    }
}

// ---------------- K5: FFN1 + GELU (MFMA, 16 rows x 256 cols) ---------------
__global__ void ffn1(const short* __restrict__ xnb, const short* __restrict__ W1P,
                     const float* __restrict__ b1, short* __restrict__ hb) {
    int bx = blockIdx.x;
    int rb = bx >> 2, nb = bx & 3;
    int r0 = rb * 16, t = threadIdx.x;
    int w = t >> 6, l = t & 63, lr = l & 15, lg = l >> 4;
    f32x4 c[4];
#pragma unroll
    for (int ni = 0; ni < 4; ++ni) c[ni] = (f32x4){0.f, 0.f, 0.f, 0.f};
#pragma unroll
    for (int kk = 0; kk < 8; ++kk) {
        bf16x8 af = *reinterpret_cast<const bf16x8*>(xnb + (size_t)(r0 + lr) * 256 + kk * 32 + lg * 8);
#pragma unroll
        for (int ni = 0; ni < 4; ++ni) {
            int cb = nb * 16 + w * 4 + ni;
            bf16x8 bf = *reinterpret_cast<const bf16x8*>(W1P + ((size_t)(cb * 8 + kk) * 64 + l) * 8);
            c[ni] = __builtin_amdgcn_mfma_f32_16x16x32_bf16(af, bf, c[ni], 0, 0, 0);
        }
    }
#pragma unroll
    for (int ni = 0; ni < 4; ++ni) {
        int col = nb * 256 + (w * 4 + ni) * 16 + lr;
        float bb = b1[col];
#pragma unroll
        for (int r = 0; r < 4; ++r) {
            int row = lg * 4 + r;
            float v = c[ni][r] + bb;
            float g = 0.5f * v * (1.f + erff(v * 0.7071067811865475f));
            hb[(size_t)(r0 + row) * 1024 + col] = f2bf(g);
        }
    }
}

// ---------------- K6: FFN2 + residual (MFMA, 16 rows, K=1024) --------------
__global__ void ffn2(const short* __restrict__ hb, const short* __restrict__ W2P,
                     const float* __restrict__ b2, const float* __restrict__ xw,
                     float* __restrict__ out) {
    int r0 = blockIdx.x * 16, t = threadIdx.x;
    int w = t >> 6, l = t & 63, lr = l & 15, lg = l >> 4;
    f32x4 c[4];
#pragma unroll
    for (int ni = 0; ni < 4; ++ni) c[ni] = (f32x4){0.f, 0.f, 0.f, 0.f};
#pragma unroll
    for (int kk = 0; kk < 32; ++kk) {
        bf16x8 af = *reinterpret_cast<const bf16x8*>(hb + (size_t)(r0 + lr) * 1024 + kk * 32 + lg * 8);
#pragma unroll
        for (int ni = 0; ni < 4; ++ni) {
            bf16x8 bf = *reinterpret_cast<const bf16x8*>(W2P + ((size_t)((w * 4 + ni) * 32 + kk) * 64 + l) * 8);
            c[ni] = __builtin_amdgcn_mfma_f32_16x16x32_bf16(af, bf, c[ni], 0, 0, 0);
        }
    }
#pragma unroll
    for (int ni = 0; ni < 4; ++ni) {
        int col = (w * 4 + ni) * 16 + lr;
        float bb = b2[col];
#pragma unroll
        for (int r = 0; r < 4; ++r) {
            int row = lg * 4 + r;
            out[(size_t)(r0 + row) * 256 + col] = xw[(size_t)(r0 + row) * 256 + col] + c[ni][r] + bb;
        }
    }
}

extern "C" void kernel_launch(void* const* d_in, const int* in_sizes, int n_in,
                              void* d_out, int out_size, void* d_ws, size_t ws_size,
                              hipStream_t stream) {
    const float* tq  = (const float*)d_in[0];
    const float* sf  = (const float*)d_in[1];
    const float* Wq  = (const float*)d_in[2];
    const float* bq  = (const float*)d_in[3];
    const float* Wk  = (const float*)d_in[4];
    const float* bk  = (const float*)d_in[5];
    const float* Wv  = (const float*)d_in[6];
    const float* bv  = (const float*)d_in[7];
    const float* Wo  = (const float*)d_in[8];
    const float* bo  = (const float*)d_in[9];
    const float* g1  = (const float*)d_in[10];
    const float* be1 = (const float*)d_in[11];
    const float* g2  = (const float*)d_in[12];
    const float* be2 = (const float*)d_in[13];
    const float* W1  = (const float*)d_in[14];
    const float* b1  = (const float*)d_in[15];
    const float* W2  = (const float*)d_in[16];
    const float* b2  = (const float*)d_in[17];

    char* wsb = (char*)d_ws;
    short* WqP = (short*)(wsb + 0);         // 128KB
    short* WkP = (short*)(wsb + 131072);    // 128KB (transposed pack)
    short* WoP = (short*)(wsb + 262144);    // 128KB
    short* WvP = (short*)(wsb + 393216);    // 128KB
    short* W1P = (short*)(wsb + 524288);    // 512KB
    short* W2P = (short*)(wsb + 1048576);   // 512KB
    float* sbw = (float*)(wsb + 1572864);   // 128KB
    short* zf  = (short*)(wsb + 1703936);   // 16MB (dead after attn)
    short* hb  = (short*)(wsb + 1703936);   // 8MB, overlays zf (written by ffn1 after attn)
    short* aob = (short*)(wsb + 18481152);  // 2MB bf16
    float* xws = (float*)(wsb + 20578304);  // 4MB
    short* xnb = (short*)(wsb + 24772608);  // 2MB bf16

    float* outp   = (float*)d_out;
    float* attnwp = (float*)d_out + 1048576;

    wconv<<<384, 256, 0, stream>>>(Wq, Wk, Wo, Wv, W1, W2, WqP, WkP, WoP, WvP, W1P, W2P);
    ln1z<<<512, 256, 0, stream>>>(tq, WqP, bq, g1, be1, WkP, bk, zf, sbw);
    attn<<<4096, 256, 0, stream>>>(sf, zf, sbw, WvP, bv, aob, attnwp);
    oproj<<<256, 256, 0, stream>>>(aob, tq, WoP, bo, g2, be2, xws, xnb);
    ffn1<<<1024, 256, 0, stream>>>(xnb, W1P, b1, hb);
    ffn2<<<256, 256, 0, stream>>>(hb, W2P, b2, xws, outp);
}